// Round 2
// baseline (148.359 us; speedup 1.0000x reference)
//
#include <hip/hip_runtime.h>

// Order-preserving map: float -> int such that f1 < f2  <=>  oi(f1) < oi(f2)
__device__ __forceinline__ int f2oi(float f) {
    int i = __float_as_int(f);
    return (i >= 0) ? i : (i ^ 0x7FFFFFFF);
}
__device__ __forceinline__ float oi2f(int i) {
    return __int_as_float((i >= 0) ? i : (i ^ 0x7FFFFFFF));
}

// INT_MIN is below every encoded real float -> "empty segment" sentinel.
#define EMPTY_SENTINEL (-2147483647 - 1)

__global__ void init_kernel(int* __restrict__ out, int n) {
    int i = blockIdx.x * blockDim.x + threadIdx.x;
    if (i < n) out[i] = EMPTY_SENTINEL;
}

// One lane per (edge, dim). tid>>5 = edge, tid&31 = dim.
// x load is fully coalesced; the 32 atomics of one edge hit one cacheline.
__global__ void scatter_max_kernel(const float* __restrict__ x,
                                   const int* __restrict__ tgt,
                                   int* __restrict__ out,
                                   long long nwork) {
    long long t = (long long)blockIdx.x * blockDim.x + threadIdx.x;
    if (t >= nwork) return;
    long long e = t >> 5;
    int d = (int)(t & 31);
    int node = tgt[e];
    float v = x[(e << 5) + d];
    atomicMax(&out[node * 32 + d], f2oi(v));
}

__global__ void finalize_kernel(int* __restrict__ buf, int n) {
    int i = blockIdx.x * blockDim.x + threadIdx.x;
    if (i < n) {
        int v = buf[i];
        float f = (v == EMPTY_SENTINEL) ? 0.0f : oi2f(v);
        reinterpret_cast<float*>(buf)[i] = f;
    }
}

extern "C" void kernel_launch(void* const* d_in, const int* in_sizes, int n_in,
                              void* d_out, int out_size, void* d_ws, size_t ws_size,
                              hipStream_t stream) {
    const float* x = (const float*)d_in[0];
    const int* edge_index = (const int*)d_in[1];   // harness passes integers as int32
    long long E = (long long)(in_sizes[1] / 2);
    const int* tgt = edge_index + E;               // row 1 of edge_index

    int* out_i = (int*)d_out;

    const int BLK = 256;

    // Phase 1: init output to sentinel
    int n_out = out_size;
    init_kernel<<<(n_out + BLK - 1) / BLK, BLK, 0, stream>>>(out_i, n_out);

    // Phase 2: scatter atomic max (E*32 lanes)
    long long nwork = E << 5;
    long long nblk = (nwork + BLK - 1) / BLK;
    scatter_max_kernel<<<(int)nblk, BLK, 0, stream>>>(x, tgt, out_i, nwork);

    // Phase 3: decode + empty->0, in place
    finalize_kernel<<<(n_out + BLK - 1) / BLK, BLK, 0, stream>>>(out_i, n_out);
}